// Round 8
// baseline (315.274 us; speedup 1.0000x reference)
//
#include <hip/hip_runtime.h>
#include <hip/hip_bf16.h>

typedef unsigned short u16;
typedef unsigned int u32;

#define N_NODES 50000
#define N_EDGES 800000
#define DHID 256
#define ELLW 64  // ELL row stride; deg is Poisson(16), P(deg>64) ~ 1e-20

typedef __attribute__((ext_vector_type(8))) _Float16 f16x8;
typedef __attribute__((ext_vector_type(4))) float f32x4;
typedef __attribute__((ext_vector_type(2))) float f32x2;

// ---------- helpers ----------
__device__ __forceinline__ u16 f2bf(float f) {
    u32 u = __float_as_uint(f);
    u32 r = (u + 0x7FFFu + ((u >> 16) & 1u)) >> 16;
    return (u16)r;
}
__device__ __forceinline__ u16 f2h(float f) {
    _Float16 h = (_Float16)f;
    union { _Float16 h; u16 u; } c; c.h = h;
    return c.u;
}
__device__ __forceinline__ void gl_lds16(const void* g, void* l) {
    __builtin_amdgcn_global_load_lds(
        (const __attribute__((address_space(1))) u32*)g,
        (__attribute__((address_space(3))) u32*)l, 16, 0, 0);
}

// ---------- zero + W-transpose: deg=0, hs zero row, W1t/W2t f16 ----------
__global__ void zero_w_kernel(int* __restrict__ deg, u32* __restrict__ hs32,
                              const float* __restrict__ W1, const float* __restrict__ W2,
                              u16* __restrict__ W1t, u16* __restrict__ W2t) {
    const int b = blockIdx.x, tid = threadIdx.x;
    if (b < 196) {
        int j = b * 256 + tid;
        if (j < N_NODES) deg[j] = 0;
        if (j < 128) hs32[(size_t)N_NODES * 128 + j] = 0;  // 512 B zero row at hs[N_NODES]
    } else {
        int idx = b - 196;  // 0..511
        int y = idx >> 8, n = idx & 255, k = tid;
        const float* W = y ? W2 : W1;
        u16* o = y ? W2t : W1t;
        o[n * 256 + k] = f2h(W[k * 256 + n]);
    }
}

// ---------- prep: x fp32 -> f16 Af ----------
#define SPLIT_BLKS 12500
__global__ void prep_kernel(const float* __restrict__ x, u16* __restrict__ xf) {
    int i = blockIdx.x * 256 + threadIdx.x;  // 3.2M float4 exact
    float4 v = ((const float4*)x)[i];
    uint2 hv;
    hv.x = (u32)f2h(v.x) | ((u32)f2h(v.y) << 16);
    hv.y = (u32)f2h(v.z) | ((u32)f2h(v.w) << 16);
    ((uint2*)xf)[i] = hv;
}

// ---------- ELL fill, 8 independent atomic->store chains per thread ----------
#define FILL_BLKS 391  // ceil(800000/2048)
__global__ void fill_kernel(const int* __restrict__ src, const int* __restrict__ dst,
                            int* __restrict__ deg, u16* __restrict__ col16) {
    const int tid = threadIdx.x;
    const int e0 = blockIdx.x * 2048 + tid;
    int ds[8], ps[8], ss[8];
    bool ok[8];
#pragma unroll
    for (int q = 0; q < 8; ++q) {
        int e = e0 + q * 256;
        ok[q] = (e < N_EDGES);
        if (ok[q]) { ds[q] = dst[e]; ss[q] = src[e]; }
    }
#pragma unroll
    for (int q = 0; q < 8; ++q)
        if (ok[q]) ps[q] = atomicAdd(&deg[ds[q]], 1);
#pragma unroll
    for (int q = 0; q < 8; ++q)
        if (ok[q] && ps[q] < ELLW) col16[(size_t)ds[q] * ELLW + ps[q]] = (u16)ss[q];
}

// ---------- GEMM (R2-exact LDS): out = (A @ W) * rsqrt(deg[row]+1), f16 A, bf16 out ----------
__global__ __launch_bounds__(256) void gemm_f16_kernel(
    const u16* __restrict__ Af, const u16* __restrict__ Bt,
    const int* __restrict__ deg, u16* __restrict__ out, int M) {
    __shared__ u16 As[128 * 32];
    __shared__ u16 Bs[128 * 32];
    const int tid = threadIdx.x;
    const int wave = tid >> 6;
    const int lane = tid & 63;
    const int wm = wave >> 1, wn = wave & 1;
    const int quad = lane >> 4, l16 = lane & 15;
    const int m0 = blockIdx.x * 128;
    const int n0 = blockIdx.y * 128;

    f32x4 acc[4][4] = {};

    const int row0 = tid >> 2, row1 = (256 + tid) >> 2;
    const int kk = (tid & 3) * 8;
    int ar0 = m0 + row0; if (ar0 >= M) ar0 = M - 1;
    int ar1 = m0 + row1; if (ar1 >= M) ar1 = M - 1;
    const size_t aoff0 = (size_t)ar0 * 256 + kk;
    const size_t aoff1 = (size_t)ar1 * 256 + kk;
    const size_t boff0 = (size_t)(n0 + row0) * 256 + kk;
    const size_t boff1 = (size_t)(n0 + row1) * 256 + kk;
    const size_t l0 = (size_t)(wave * 64) * 8;
    const size_t l1 = (size_t)(256 + wave * 64) * 8;

    for (int ko = 0; ko < 8; ++ko) {
        const int koff = ko * 32;
        __syncthreads();
        gl_lds16(Af + aoff0 + koff, &As[l0]);
        gl_lds16(Af + aoff1 + koff, &As[l1]);
        gl_lds16(Bt + boff0 + koff, &Bs[l0]);
        gl_lds16(Bt + boff1 + koff, &Bs[l1]);
        asm volatile("s_waitcnt vmcnt(0)" ::: "memory");
        __syncthreads();

        f16x8 af[4], bf[4];
#pragma unroll
        for (int mi = 0; mi < 4; ++mi)
            af[mi] = *(const f16x8*)&As[(wm * 64 + mi * 16 + l16) * 32 + quad * 8];
#pragma unroll
        for (int ni = 0; ni < 4; ++ni)
            bf[ni] = *(const f16x8*)&Bs[(wn * 64 + ni * 16 + l16) * 32 + quad * 8];
#pragma unroll
        for (int mi = 0; mi < 4; ++mi)
#pragma unroll
            for (int ni = 0; ni < 4; ++ni)
                acc[mi][ni] = __builtin_amdgcn_mfma_f32_16x16x32_f16(af[mi], bf[ni], acc[mi][ni], 0, 0, 0);
    }

#pragma unroll
    for (int mi = 0; mi < 4; ++mi) {
#pragma unroll
        for (int r = 0; r < 4; ++r) {
            int row = m0 + wm * 64 + mi * 16 + quad * 4 + r;
            if (row < M) {
                float s = rsqrtf((float)deg[row] + 1.0f);
#pragma unroll
                for (int ni = 0; ni < 4; ++ni) {
                    int c = n0 + wn * 64 + ni * 16 + l16;
                    out[(size_t)row * 256 + c] = f2bf(acc[mi][ni][r] * s);
                }
            }
        }
    }
}

// ---------- aggregation (R2 proven) with node offset: half-range dispatches ----------
__global__ __launch_bounds__(256) void agg_kernel(
    const u16* __restrict__ hs, const u16* __restrict__ col16,
    const int* __restrict__ deg, const float* __restrict__ bias,
    u16* __restrict__ out_f16, float* __restrict__ out_f,
    int mode, int off, int Nn) {
    const int wave = threadIdx.x >> 6, lane = threadIdx.x & 63;
    const int i = off + blockIdx.x * 4 + wave;
    if (i >= Nn) return;

    const int cnt = deg[i];
    const size_t ebase = (size_t)i * ELLW;
    int entry = Nn;  // zero-row pad
    if (lane == 0) entry = i;
    else if (lane - 1 < cnt) entry = (int)col16[ebase + lane - 1];
    int entries = cnt + 1;
    if (entries > 64) entries = 64;
    const int nb = (entries + 3) >> 2;
    const size_t lofs = (size_t)lane * 4;

    f32x2 a01 = {0.f, 0.f}, a23 = {0.f, 0.f};

#define ISSUE(b, x0, x1, x2, x3)                                                \
    {                                                                           \
        int e0 = __builtin_amdgcn_readlane(entry, (b) * 4 + 0);                 \
        int e1 = __builtin_amdgcn_readlane(entry, (b) * 4 + 1);                 \
        int e2 = __builtin_amdgcn_readlane(entry, (b) * 4 + 2);                 \
        int e3 = __builtin_amdgcn_readlane(entry, (b) * 4 + 3);                 \
        x0 = *(const uint2*)(hs + (size_t)e0 * 256 + lofs);                     \
        x1 = *(const uint2*)(hs + (size_t)e1 * 256 + lofs);                     \
        x2 = *(const uint2*)(hs + (size_t)e2 * 256 + lofs);                     \
        x3 = *(const uint2*)(hs + (size_t)e3 * 256 + lofs);                     \
    }
#define ACCUM(v)                                                                \
    {                                                                           \
        f32x2 p0, p1;                                                           \
        p0.x = __uint_as_float(v.x << 16);                                      \
        p0.y = __uint_as_float(v.x & 0xffff0000u);                              \
        p1.x = __uint_as_float(v.y << 16);                                      \
        p1.y = __uint_as_float(v.y & 0xffff0000u);                              \
        a01 += p0; a23 += p1;                                                   \
    }

    uint2 c0, c1, c2, c3, d0, d1, d2, d3, n0v, n1v, n2v, n3v;
    ISSUE(0, c0, c1, c2, c3);
    if (nb > 1) ISSUE(1, d0, d1, d2, d3);
    for (int b = 0; b < nb; ++b) {
        const bool more2 = (b + 2 < nb);
        if (more2) ISSUE(b + 2, n0v, n1v, n2v, n3v);
        ACCUM(c0); ACCUM(c1); ACCUM(c2); ACCUM(c3);
        c0 = d0; c1 = d1; c2 = d2; c3 = d3;
        d0 = n0v; d1 = n1v; d2 = n2v; d3 = n3v;
    }
    // rare tail: deg > 63 (ELL slot 63; slots beyond ELLW were dropped, P~0)
    {
        int cap = cnt < ELLW ? cnt : ELLW;
        for (int j = 63; j < cap; ++j) {
            int s = (int)col16[ebase + j];
            uint2 v = *(const uint2*)(hs + (size_t)s * 256 + lofs);
            ACCUM(v);
        }
    }
#undef ISSUE
#undef ACCUM

    const float inv = rsqrtf((float)cnt + 1.0f);
    float4 bb = *(const float4*)(bias + lane * 4);
    float r0 = fmaxf(fmaf(a01.x, inv, bb.x), 0.0f);
    float r1 = fmaxf(fmaf(a01.y, inv, bb.y), 0.0f);
    float r2 = fmaxf(fmaf(a23.x, inv, bb.z), 0.0f);
    float r3 = fmaxf(fmaf(a23.y, inv, bb.w), 0.0f);
    const size_t o = (size_t)i * 256 + lane * 4;
    if (mode == 0) {
        u16 h0 = f2h(r0), h1 = f2h(r1), h2 = f2h(r2), h3 = f2h(r3);
        uint2 w;
        w.x = (u32)h0 | ((u32)h1 << 16);
        w.y = (u32)h2 | ((u32)h3 << 16);
        *(uint2*)(out_f16 + o) = w;
    } else {
        *(float4*)(out_f + o) = make_float4(r0, r1, r2, r3);
    }
}

extern "C" void kernel_launch(void* const* d_in, const int* in_sizes, int n_in,
                              void* d_out, int out_size, void* d_ws, size_t ws_size,
                              hipStream_t stream) {
    const float* x = (const float*)d_in[0];
    const int* ei = (const int*)d_in[1];
    const float* W1 = (const float*)d_in[2];
    const float* b1 = (const float*)d_in[3];
    const float* W2 = (const float*)d_in[4];
    const float* b2 = (const float*)d_in[5];
    float* out = (float*)d_out;

    const int Nn = N_NODES, E = N_EDGES;
    const int* srcp = ei;
    const int* dstp = ei + E;

    char* p = (char*)d_ws;
    auto take = [&](size_t bytes) -> void* {
        void* r = (void*)p;
        p += (bytes + 255) & ~(size_t)255;
        return r;
    };
    u16* hs    = (u16*)take((size_t)(Nn + 1) * DHID * 2);  // bf16, +1 zero row
    u16* col16 = (u16*)take((size_t)Nn * ELLW * 2);        // ELL, 6.4 MB
    int* deg   = (int*)take((size_t)Nn * 4);
    u16* W1t   = (u16*)take(256 * 256 * 2);
    u16* W2t   = (u16*)take(256 * 256 * 2);
    // f16 A buffer (x-f16 for gemm1; reused as agg1 output feeding gemm2).
    size_t used = (size_t)(p - (char*)d_ws);
    size_t af_bytes = (size_t)Nn * DHID * 2;  // 25.6 MB
    u16* Af = (ws_size >= used + af_bytes) ? (u16*)take(af_bytes) : (u16*)d_out;

    zero_w_kernel<<<708, 256, 0, stream>>>(deg, (u32*)hs, W1, W2, W1t, W2t);
    prep_kernel<<<SPLIT_BLKS, 256, 0, stream>>>(x, Af);
    fill_kernel<<<FILL_BLKS, 256, 0, stream>>>(srcp, dstp, deg, col16);

    const int gm = (Nn + 127) / 128;  // 391
    const int gah = 6250;             // 25000 nodes per half
    // layer 1
    gemm_f16_kernel<<<dim3(gm, 2), 256, 0, stream>>>(Af, W1t, deg, hs, Nn);
    agg_kernel<<<gah, 256, 0, stream>>>(hs, col16, deg, b1, Af, nullptr, 0, 0, Nn);
    agg_kernel<<<gah, 256, 0, stream>>>(hs, col16, deg, b1, Af, nullptr, 0, 25000, Nn);
    // layer 2
    gemm_f16_kernel<<<dim3(gm, 2), 256, 0, stream>>>(Af, W2t, deg, hs, Nn);
    agg_kernel<<<gah, 256, 0, stream>>>(hs, col16, deg, b2, nullptr, out, 1, 0, Nn);
    agg_kernel<<<gah, 256, 0, stream>>>(hs, col16, deg, b2, nullptr, out, 1, 25000, Nn);
}